// Round 1
// baseline (688.193 us; speedup 1.0000x reference)
//
#include <hip/hip_runtime.h>
#include <stdint.h>

#define GLOBAL_AS __attribute__((address_space(1)))
#define LDS_AS    __attribute__((address_space(3)))

typedef __attribute__((ext_vector_type(8))) __bf16 bf16x8;
typedef __attribute__((ext_vector_type(4))) float  f32x4;

// ---------- helpers ----------
__device__ __forceinline__ uint16_t f2b(float f) {           // fp32 -> bf16 RNE
  uint32_t u = __float_as_uint(f);
  u += 0x7fffu + ((u >> 16) & 1u);
  return (uint16_t)(u >> 16);
}
__device__ __forceinline__ float b2f_lo(uint32_t p) { return __uint_as_float(p << 16); }
__device__ __forceinline__ float b2f_hi(uint32_t p) { return __uint_as_float(p & 0xffff0000u); }

// async 16B global -> LDS (wave-uniform base + lane*16 layout)
#define ASYNC16(gptr, lptr)                                                     \
  __builtin_amdgcn_global_load_lds((GLOBAL_AS void*)(uintptr_t)(gptr),          \
                                   (LDS_AS void*)(lptr), 16, 0, 0)

// ---------- 1. encoder fp32 -> bf16 (8 elems/thread) ----------
__global__ __launch_bounds__(256) void convert_enc(const float4* __restrict__ in,
                                                   uint4* __restrict__ out) {
  int i = blockIdx.x * 256 + threadIdx.x;
  float4 a = in[2 * i], b = in[2 * i + 1];
  uint4 o;
  o.x = (uint32_t)f2b(a.x) | ((uint32_t)f2b(a.y) << 16);
  o.y = (uint32_t)f2b(a.z) | ((uint32_t)f2b(a.w) << 16);
  o.z = (uint32_t)f2b(b.x) | ((uint32_t)f2b(b.y) << 16);
  o.w = (uint32_t)f2b(b.z) | ((uint32_t)f2b(b.w) << 16);
  out[i] = o;
}

// ---------- 2. W_a (K x N) -> WT bf16 (N x K), LDS-tiled transpose ----------
__global__ __launch_bounds__(256) void convert_WT(const float* __restrict__ W,
                                                  uint16_t* __restrict__ WT) {
  __shared__ float tile[64][65];
  int k0 = (blockIdx.x & 15) * 64;
  int n0 = (blockIdx.x >> 4) * 64;
  #pragma unroll
  for (int it = 0; it < 16; ++it) {
    int idx = it * 256 + threadIdx.x;
    int kr = idx >> 6, nc = idx & 63;
    tile[kr][nc] = W[(size_t)(k0 + kr) * 1024 + n0 + nc];
  }
  __syncthreads();
  #pragma unroll
  for (int it = 0; it < 16; ++it) {
    int idx = it * 256 + threadIdx.x;
    int nr = idx >> 6, kc = idx & 63;
    WT[(size_t)(n0 + nr) * 1024 + k0 + kc] = f2b(tile[kc][nr]);
  }
}

// ---------- 3. u[b,f] = sum_d dec_last[b,d] * U[d,f]  (fp32) ----------
__global__ __launch_bounds__(256) void compute_u(const float* __restrict__ dec,
                                                 const float* __restrict__ U,
                                                 float* __restrict__ u) {
  int b = blockIdx.x >> 2;
  int f = ((blockIdx.x & 3) << 8) + threadIdx.x;
  const float* dl = dec + (size_t)b * 64 * 1024 + 63 * 1024;  // last decoder step
  __shared__ float sdec[1024];
  for (int i = threadIdx.x; i < 1024; i += 256) sdec[i] = dl[i];
  __syncthreads();
  float acc = 0.f;
  #pragma unroll 8
  for (int d = 0; d < 1024; ++d) acc = fmaf(sdec[d], U[(size_t)d * 1024 + f], acc);
  u[b * 1024 + f] = acc;
}

// ---------- 4. fused GEMM: scores[r] += sum_f v[f]*tanh((A@W)[r,f] + u[b,f]) ----
// A: bf16 [65536 x 1024] row-major (k contig). BT: bf16 [1024 x 1024] (n-major, k contig).
// 128x128 tile, BK=32, 4 waves (2x2), 4x4 MFMA tiles of 16x16x32 per wave.
__global__ __launch_bounds__(256) void gemm_score(const uint16_t* __restrict__ A,
                                                  const uint16_t* __restrict__ BT,
                                                  const float* __restrict__ u,
                                                  const float* __restrict__ v,
                                                  float* __restrict__ scores) {
  __shared__ __bf16 sA[128 * 32];
  __shared__ __bf16 sB[128 * 32];

  // swizzle: 64-block groups = 8 mtiles x 8 ntiles; siblings of an mtile share bx%8
  int bx = blockIdx.x;
  int g = bx >> 6, r = bx & 63;
  int mtile = g * 8 + (r & 7);
  int ntile = r >> 3;

  int tid = threadIdx.x;
  int lane = tid & 63;
  int wid  = tid >> 6;
  int wm = (wid & 1) * 64;
  int wn = (wid >> 1) * 64;
  int quad = lane >> 4, nib = lane & 15;

  f32x4 acc[4][4];
  #pragma unroll
  for (int i = 0; i < 4; ++i)
    #pragma unroll
    for (int j = 0; j < 4; ++j) acc[i][j] = (f32x4){0.f, 0.f, 0.f, 0.f};

  const int rowA = mtile * 128;
  const int rowB = ntile * 128;
  const int c0 = tid, c1 = tid + 256;  // 16B chunks: row=c>>2, kchunk=c&3

  for (int k0 = 0; k0 < 1024; k0 += 32) {
    __syncthreads();
    ASYNC16(A  + (size_t)(rowA + (c0 >> 2)) * 1024 + k0 + (c0 & 3) * 8, sA + c0 * 8);
    ASYNC16(A  + (size_t)(rowA + (c1 >> 2)) * 1024 + k0 + (c1 & 3) * 8, sA + c1 * 8);
    ASYNC16(BT + (size_t)(rowB + (c0 >> 2)) * 1024 + k0 + (c0 & 3) * 8, sB + c0 * 8);
    ASYNC16(BT + (size_t)(rowB + (c1 >> 2)) * 1024 + k0 + (c1 & 3) * 8, sB + c1 * 8);
    __syncthreads();

    bf16x8 af[4], bf[4];
    #pragma unroll
    for (int i = 0; i < 4; ++i)
      af[i] = *(const bf16x8*)(sA + (wm + i * 16 + nib) * 32 + quad * 8);
    #pragma unroll
    for (int j = 0; j < 4; ++j)
      bf[j] = *(const bf16x8*)(sB + (wn + j * 16 + nib) * 32 + quad * 8);

    #pragma unroll
    for (int i = 0; i < 4; ++i)
      #pragma unroll
      for (int j = 0; j < 4; ++j)
        acc[i][j] = __builtin_amdgcn_mfma_f32_16x16x32_bf16(af[i], bf[j], acc[i][j], 0, 0, 0);
  }

  // epilogue: +u, tanh, dot with v along this block's 128 cols, reduce, atomicAdd
  int b = rowA >> 11;  // 2048 rows per batch; 128 | 2048 so b is block-uniform
  float vv[4], uu[4];
  #pragma unroll
  for (int j = 0; j < 4; ++j) {
    int col = ntile * 128 + wn + j * 16 + nib;
    vv[j] = v[col];
    uu[j] = u[b * 1024 + col];
  }
  #pragma unroll
  for (int i = 0; i < 4; ++i) {
    int rbase = rowA + wm + i * 16 + quad * 4;  // C/D: row = quad*4 + reg, col = nib
    #pragma unroll
    for (int reg = 0; reg < 4; ++reg) {
      float s = 0.f;
      #pragma unroll
      for (int j = 0; j < 4; ++j) s += vv[j] * tanhf(acc[i][j][reg] + uu[j]);
      s += __shfl_xor(s, 1);
      s += __shfl_xor(s, 2);
      s += __shfl_xor(s, 4);
      s += __shfl_xor(s, 8);
      if (nib == 0) atomicAdd(&scores[rbase + reg], s);
    }
  }
}

// ---------- 5. softmax over t (2048) per batch ----------
__global__ __launch_bounds__(256) void softmax_k(const float* __restrict__ scores,
                                                 float* __restrict__ wout) {
  int b = blockIdx.x, tid = threadIdx.x;
  __shared__ float red[4];
  float sv[8];
  float mx = -1e30f;
  #pragma unroll
  for (int i = 0; i < 8; ++i) {
    sv[i] = scores[b * 2048 + i * 256 + tid];
    mx = fmaxf(mx, sv[i]);
  }
  #pragma unroll
  for (int off = 1; off < 64; off <<= 1) mx = fmaxf(mx, __shfl_xor(mx, off));
  if ((tid & 63) == 0) red[tid >> 6] = mx;
  __syncthreads();
  mx = fmaxf(fmaxf(red[0], red[1]), fmaxf(red[2], red[3]));
  __syncthreads();
  float sum = 0.f;
  #pragma unroll
  for (int i = 0; i < 8; ++i) {
    sv[i] = __expf(sv[i] - mx);
    sum += sv[i];
  }
  #pragma unroll
  for (int off = 1; off < 64; off <<= 1) sum += __shfl_xor(sum, off);
  if ((tid & 63) == 0) red[tid >> 6] = sum;
  __syncthreads();
  float inv = 1.0f / (red[0] + red[1] + red[2] + red[3]);
  #pragma unroll
  for (int i = 0; i < 8; ++i) wout[b * 2048 + i * 256 + tid] = sv[i] * inv;
}

// ---------- 6. context[b,e] = sum_t w[b,t] * enc[b,t,e] ----------
__global__ __launch_bounds__(256) void context_k(const uint16_t* __restrict__ encA,
                                                 const float* __restrict__ w,
                                                 float* __restrict__ ctx) {
  int b = blockIdx.x >> 4, ch = blockIdx.x & 15;
  int t0 = ch * 128;
  __shared__ float lw[128];
  if (threadIdx.x < 128) lw[threadIdx.x] = w[b * 2048 + t0 + threadIdx.x];
  __syncthreads();
  int e0 = threadIdx.x * 4;
  float a0 = 0.f, a1 = 0.f, a2 = 0.f, a3 = 0.f;
  const uint16_t* base = encA + (size_t)b * 2048 * 1024 + (size_t)t0 * 1024 + e0;
  #pragma unroll 4
  for (int t = 0; t < 128; ++t) {
    uint2 p = *(const uint2*)(base + (size_t)t * 1024);
    float wt = lw[t];
    a0 = fmaf(wt, b2f_lo(p.x), a0);
    a1 = fmaf(wt, b2f_hi(p.x), a1);
    a2 = fmaf(wt, b2f_lo(p.y), a2);
    a3 = fmaf(wt, b2f_hi(p.y), a3);
  }
  atomicAdd(&ctx[b * 1024 + e0 + 0], a0);
  atomicAdd(&ctx[b * 1024 + e0 + 1], a1);
  atomicAdd(&ctx[b * 1024 + e0 + 2], a2);
  atomicAdd(&ctx[b * 1024 + e0 + 3], a3);
}

extern "C" void kernel_launch(void* const* d_in, const int* in_sizes, int n_in,
                              void* d_out, int out_size, void* d_ws, size_t ws_size,
                              hipStream_t stream) {
  const float* enc = (const float*)d_in[0];  // (32, 2048, 1024)
  const float* dec = (const float*)d_in[1];  // (32, 64, 1024)
  const float* Wa  = (const float*)d_in[2];  // (1024, 1024)
  const float* Ua  = (const float*)d_in[3];  // (1024, 1024)
  const float* Va  = (const float*)d_in[4];  // (1024, 1)

  float* out = (float*)d_out;
  float* ctx = out;                 // 32*1024
  float* wts = out + 32 * 1024;     // 32*2048*1

  char* ws = (char*)d_ws;
  uint16_t* encA  = (uint16_t*)ws;                           // 128 MB bf16 encoder
  uint16_t* WT    = (uint16_t*)(ws + 134217728);             // 2 MB bf16 W^T
  float*    ub    = (float*)  (ws + 136314880);              // 128 KB u[b,f]
  float*    score = (float*)  (ws + 136445952);              // 256 KB scores

  hipMemsetAsync(ctx, 0, 32 * 1024 * sizeof(float), stream);
  hipMemsetAsync(score, 0, 65536 * sizeof(float), stream);

  convert_enc<<<32768, 256, 0, stream>>>((const float4*)enc, (uint4*)encA);
  convert_WT<<<256, 256, 0, stream>>>(Wa, WT);
  compute_u<<<128, 256, 0, stream>>>(dec, Ua, ub);
  gemm_score<<<4096, 256, 0, stream>>>(encA, WT, ub, Va, score);
  softmax_k<<<32, 256, 0, stream>>>(score, wts);
  context_k<<<512, 256, 0, stream>>>(encA, wts, ctx);
}